// Round 4
// baseline (318.350 us; speedup 1.0000x reference)
//
#include <hip/hip_runtime.h>
#include <hip/hip_bf16.h>

typedef unsigned short u16;
typedef __bf16 bf16x8 __attribute__((ext_vector_type(8)));
typedef float floatx4 __attribute__((ext_vector_type(4)));
typedef unsigned short ushort8 __attribute__((ext_vector_type(8)));

#define GLOBAL_AS(p) ((const __attribute__((address_space(1))) void*)(p))
#define LDS_AS(p) ((__attribute__((address_space(3))) void*)(p))

constexpr int NB = 8192;
constexpr int DIN = 512;
constexpr int DH = 2048;
constexpr int DOUT = 512;
constexpr int NEXP = 8;
constexpr int ROWCAP = NB + NEXP * 128;  // 128-padded segments
constexpr int MTL = 12;                  // launched m-tiles/expert; loop covers beyond
constexpr int TILE = 8192;               // elements in a 128x64 bf16 tile

__device__ __forceinline__ u16 f2bf(float f) {
    unsigned u = __builtin_bit_cast(unsigned, f);
    unsigned r = u + 0x7FFFu + ((u >> 16) & 1u);
    return (u16)(r >> 16);
}

// element offset within a 128x64 tile for (row, klocal), xor-swizzled 16B chunks
__device__ __forceinline__ int slot_off(int row, int kl) {
    return row * 64 + ((((kl >> 3) ^ (row & 7)) << 3) | (kl & 7));
}

// ---------------- routing ----------------
__global__ void init_kernel(int* cnt) {
    if (threadIdx.x < NEXP) cnt[threadIdx.x] = 0;
}

__global__ void hist_kernel(const int* __restrict__ groups, int* __restrict__ cnt) {
    __shared__ int lc[NEXP];
    if (threadIdx.x < NEXP) lc[threadIdx.x] = 0;
    __syncthreads();
    int i = blockIdx.x * 256 + threadIdx.x;
    atomicAdd(&lc[groups[i]], 1);
    __syncthreads();
    if (threadIdx.x < NEXP) atomicAdd(&cnt[threadIdx.x], lc[threadIdx.x]);
}

__global__ void scan_kernel(const int* cnt, int* offs, int* curs) {
    if (threadIdx.x == 0 && blockIdx.x == 0) {
        int run = 0;
        for (int e = 0; e < NEXP; ++e) {
            offs[e] = run; curs[e] = run;
            run += ((cnt[e] + 127) >> 7) << 7;   // 128-aligned segments
        }
    }
}

// ---------------- fused prep: W1-transpose | W2-transpose | init_out | gather ----------------
// grid.x = 2048 (W1) + 2048 (W2) + 4096 (init_out) + 128 (gather) = 8320
__global__ __launch_bounds__(256) void prep_kernel(
        const float* __restrict__ x, const int* __restrict__ groups,
        const float* __restrict__ W1, const float* __restrict__ W2,
        const float* __restrict__ b2, float* __restrict__ out,
        int* __restrict__ curs, int* __restrict__ perm,
        u16* __restrict__ xsT, u16* __restrict__ w1tT, u16* __restrict__ w2tT) {
    int bx = blockIdx.x;
    int t = threadIdx.x;
    if (bx < 4096) {
        // weight transpose+convert+tile: src [E][K][N] row-major -> tiled [e][nt][kt][128][64]
        __shared__ float tile[64][65];
        bool isW1 = bx < 2048;
        int b = isW1 ? bx : bx - 2048;
        int e = b >> 8;
        int q = b & 255;
        int C = isW1 ? DH : DOUT;         // N-dim
        int NTP = C >> 7;                 // n-tiles per expert (16 / 4)
        int KTP = isW1 ? (DIN >> 6) : (DH >> 6);  // k-tiles per expert (8 / 32)
        int rt = isW1 ? (q >> 5) : (q >> 3);      // k 64-tile idx
        int ct = isW1 ? (q & 31) : (q & 7);       // n 64-tile idx
        const float* s = (isW1 ? W1 : W2) + (size_t)e * (isW1 ? DIN * DH : DH * DOUT);
        u16* d = isW1 ? w1tT : w2tT;
        int r0 = rt * 64, c0 = ct * 64;
        for (int i = 0; i < 4; ++i) {
            int r = (t >> 4) + i * 16;
            int c = (t & 15) * 4;
            const float4 v = *(const float4*)&s[(size_t)(r0 + r) * C + c0 + c];
            tile[r][c] = v.x; tile[r][c + 1] = v.y; tile[r][c + 2] = v.z; tile[r][c + 3] = v.w;
        }
        __syncthreads();
        for (int i = 0; i < 4; ++i) {
            int c = (t >> 4) + i * 16;    // n-local
            int r = (t & 15) * 4;         // k-local, 4 consecutive
            int n = c0 + c, k = r0 + r;
            ushort4 o;
            o.x = f2bf(tile[r][c]); o.y = f2bf(tile[r + 1][c]);
            o.z = f2bf(tile[r + 2][c]); o.w = f2bf(tile[r + 3][c]);
            size_t off = ((size_t)(e * NTP + (n >> 7)) * KTP + (k >> 6)) * TILE
                         + slot_off(n & 127, k & 63);
            *(ushort4*)&d[off] = o;
        }
    } else if (bx < 8192) {
        // out[b][:] = b2[groups[b]][:]
        int idx = (bx - 4096) * 256 + t;
        int row = idx >> 7;
        int c = (idx & 127) * 4;
        int g = groups[row];
        *(float4*)&out[(size_t)row * DOUT + c] = *(const float4*)&b2[(size_t)g * DOUT + c];
    } else {
        // gather+scatter: 64 rows per block -> xsT tiled, perm
        __shared__ int spos[64];
        int g = bx - 8192;
        if (t < 64) {
            int i = g * 64 + t;
            int e = groups[i];
            int pos = atomicAdd(&curs[e], 1);
            perm[pos] = i;
            spos[t] = pos;
        }
        __syncthreads();
        int r = t >> 2, sseg = t & 3;    // 4 threads per row, 128 k each
        int i = g * 64 + r;
        int pos = spos[r];
        const float* src = x + (size_t)i * DIN + sseg * 128;
        int lp = pos & 127;
        size_t tb = (size_t)(pos >> 7) * 8 * TILE + (size_t)lp * 64;
        for (int cc = 0; cc < 16; ++cc) {
            int k = sseg * 128 + cc * 8;
            const float4 a = *(const float4*)&src[cc * 8];
            const float4 bb = *(const float4*)&src[cc * 8 + 4];
            ushort8 o;
            o[0] = f2bf(a.x); o[1] = f2bf(a.y); o[2] = f2bf(a.z); o[3] = f2bf(a.w);
            o[4] = f2bf(bb.x); o[5] = f2bf(bb.y); o[6] = f2bf(bb.z); o[7] = f2bf(bb.w);
            int kl = k & 63;
            *(ushort8*)&xsT[tb + (size_t)(k >> 6) * TILE
                            + ((((kl >> 3) ^ (lp & 7)) << 3))] = o;
        }
    }
}

// ---------------- GEMM building blocks ----------------
__device__ __forceinline__ void stage_tile(const u16* Atile, const u16* Btile,
                                           u16* As, u16* Bs, int tid, int w) {
    for (int j = 0; j < 4; ++j) {
        int off = (j * 256 + w * 64) * 8;            // wave-uniform; HW adds lane*16B
        const u16* ga = Atile + (size_t)(j * 256 + tid) * 8;   // contiguous 1KB per wave
        const u16* gb = Btile + (size_t)(j * 256 + tid) * 8;
        __builtin_amdgcn_global_load_lds(GLOBAL_AS(ga), LDS_AS(As + off), 16, 0, 0);
        __builtin_amdgcn_global_load_lds(GLOBAL_AS(gb), LDS_AS(Bs + off), 16, 0, 0);
    }
}

__device__ __forceinline__ void compute_tile(const u16* As, const u16* Bs, floatx4 acc[4][4],
                                             int wm, int wn, int q, int li) {
    for (int s = 0; s < 2; ++s) {
        int c0 = s * 4 + q;
        bf16x8 af[4], bfr[4];
        for (int fm = 0; fm < 4; ++fm) {
            int m = wm * 64 + fm * 16 + li;
            af[fm] = *(const bf16x8*)&As[m * 64 + ((c0 ^ (m & 7)) << 3)];
        }
        for (int fn = 0; fn < 4; ++fn) {
            int n = wn * 64 + fn * 16 + li;
            bfr[fn] = *(const bf16x8*)&Bs[n * 64 + ((c0 ^ (n & 7)) << 3)];
        }
        for (int fm = 0; fm < 4; ++fm)
            for (int fn = 0; fn < 4; ++fn)
                acc[fm][fn] = __builtin_amdgcn_mfma_f32_16x16x32_bf16(
                    af[fm], bfr[fn], acc[fm][fn], 0, 0, 0);
    }
}

// 128x128 tile, 8 phases of BK=64, double-buffered, tile-contiguous operands.
// Grid 1-D: e = bx&7 (XCD affinity). Pass A: 8x16x12=1536 blocks. Pass B: 8x4x4x12=1536.
template <bool RELU>
__global__ __launch_bounds__(256) void gemm_tiles(
        const u16* __restrict__ At, const u16* __restrict__ Bt,
        const float* __restrict__ bias, u16* __restrict__ hsT,
        float* __restrict__ out_f, const int* __restrict__ cnt,
        const int* __restrict__ offs, const int* __restrict__ perm) {
    int bx = blockIdx.x;
    int e = bx & 7;
    int r = bx >> 3;
    int nt, ks, mt0;
    if (RELU) { nt = r & 15; mt0 = r >> 4; ks = 0; }
    else      { nt = r & 3; r >>= 2; ks = r & 3; mt0 = r >> 2; }
    int count = cnt[e];
    int seg = offs[e];

    __shared__ u16 As0[TILE];
    __shared__ u16 Bs0[TILE];
    __shared__ u16 As1[TILE];
    __shared__ u16 Bs1[TILE];

    int tid = threadIdx.x;
    int l = tid & 63, w = tid >> 6;
    int wm = w & 1, wn = w >> 1;
    int q = l >> 4, li = l & 15;

    for (int mt = mt0; mt * 128 < count; mt += MTL) {
        int mtG = (seg >> 7) + mt;
        const u16* Abase;
        const u16* Bbase;
        if (RELU) {
            Abase = At + (size_t)mtG * 8 * TILE;
            Bbase = Bt + (size_t)(e * 16 + nt) * 8 * TILE;
        } else {
            Abase = At + ((size_t)mtG * 32 + ks * 8) * TILE;
            Bbase = Bt + ((size_t)(e * 4 + nt) * 32 + ks * 8) * TILE;
        }

        floatx4 acc[4][4];
        for (int a = 0; a < 4; ++a)
            for (int b = 0; b < 4; ++b) acc[a][b] = (floatx4)0.0f;

        stage_tile(Abase, Bbase, As0, Bs0, tid, w);
        for (int p = 0; p < 8; p += 2) {
            __syncthreads();
            if (p + 1 < 8)
                stage_tile(Abase + (p + 1) * TILE, Bbase + (p + 1) * TILE, As1, Bs1, tid, w);
            compute_tile(As0, Bs0, acc, wm, wn, q, li);
            __syncthreads();
            if (p + 2 < 8)
                stage_tile(Abase + (p + 2) * TILE, Bbase + (p + 2) * TILE, As0, Bs0, tid, w);
            compute_tile(As1, Bs1, acc, wm, wn, q, li);
        }

        // epilogue: C/D layout col=lane&15, row=(lane>>4)*4+reg
        for (int fn = 0; fn < 4; ++fn) {
            int ncol = nt * 128 + wn * 64 + fn * 16 + li;
            float bv = RELU ? bias[(size_t)e * DH + ncol] : 0.0f;
            size_t tb = RELU ? ((size_t)mtG * 32 + (ncol >> 6)) * TILE : 0;
            for (int fm = 0; fm < 4; ++fm) {
                int lrow0 = wm * 64 + fm * 16 + q * 4;
                for (int rr = 0; rr < 4; ++rr) {
                    int lrow = lrow0 + rr;
                    int mrow = mt * 128 + lrow;
                    if (mrow < count) {
                        float v = acc[fm][fn][rr] + bv;
                        if (RELU) {
                            v = v > 0.0f ? v : 0.0f;
                            hsT[tb + slot_off(lrow, ncol & 63)] = f2bf(v);
                        } else {
                            int orow = perm[seg + mrow];
                            atomicAdd(&out_f[(size_t)orow * DOUT + ncol], v);
                        }
                    }
                }
            }
        }
        __syncthreads();   // protect LDS reuse across mt iterations
    }
}

// ---------------- launch ----------------
extern "C" void kernel_launch(void* const* d_in, const int* in_sizes, int n_in,
                              void* d_out, int out_size, void* d_ws, size_t ws_size,
                              hipStream_t stream) {
    const float* x = (const float*)d_in[0];
    const int* groups = (const int*)d_in[1];
    const float* W1 = (const float*)d_in[2];
    const float* b1 = (const float*)d_in[3];
    const float* W2 = (const float*)d_in[4];
    const float* b2 = (const float*)d_in[5];
    float* out = (float*)d_out;

    char* ws = (char*)d_ws;
    size_t o = 0;
    auto alloc = [&](size_t bytes) {
        void* p = ws + o;
        o = (o + bytes + 255) & ~(size_t)255;
        return p;
    };
    int* cnt = (int*)alloc(NEXP * 4);
    int* offs = (int*)alloc(NEXP * 4);
    int* curs = (int*)alloc(NEXP * 4);
    int* perm = (int*)alloc((size_t)ROWCAP * 4);
    u16* xsT = (u16*)alloc((size_t)(ROWCAP / 128) * 8 * TILE * 2);    // ~9.4 MB
    u16* w1tT = (u16*)alloc((size_t)NEXP * DIN * DH * 2);             // 16.8 MB
    u16* w2tT = (u16*)alloc((size_t)NEXP * DH * DOUT * 2);            // 16.8 MB
    u16* hsT = (u16*)alloc((size_t)(ROWCAP / 128) * 32 * TILE * 2);   // ~37.7 MB

    init_kernel<<<1, 64, 0, stream>>>(cnt);
    hist_kernel<<<NB / 256, 256, 0, stream>>>(groups, cnt);
    scan_kernel<<<1, 64, 0, stream>>>(cnt, offs, curs);
    prep_kernel<<<8320, 256, 0, stream>>>(x, groups, W1, W2, b2, out,
                                          curs, perm, xsT, w1tT, w2tT);
    // pass A: h = relu(x @ W1 + b1)
    gemm_tiles<true><<<NEXP * 16 * MTL, 256, 0, stream>>>(
        xsT, w1tT, b1, hsT, nullptr, cnt, offs, perm);
    // pass B: out += h @ W2 (4-way k-split, atomic)
    gemm_tiles<false><<<NEXP * 4 * 4 * MTL, 256, 0, stream>>>(
        hsT, w2tT, nullptr, nullptr, out, cnt, offs, perm);
}

// Round 5
// 314.477 us; speedup vs baseline: 1.0123x; 1.0123x over previous
//
#include <hip/hip_runtime.h>
#include <hip/hip_bf16.h>

typedef unsigned short u16;
typedef __bf16 bf16x8 __attribute__((ext_vector_type(8)));
typedef float floatx4 __attribute__((ext_vector_type(4)));
typedef unsigned short ushort8 __attribute__((ext_vector_type(8)));

#define GLOBAL_AS(p) ((const __attribute__((address_space(1))) void*)(p))
#define LDS_AS(p) ((__attribute__((address_space(3))) void*)(p))

constexpr int NB = 8192;
constexpr int DIN = 512;
constexpr int DH = 2048;
constexpr int DOUT = 512;
constexpr int NEXP = 8;
constexpr int ROWCAP = NB + NEXP * 128;  // 128-padded segments
constexpr int MTL = 8;                   // launched m-tiles/expert; loop covers beyond
constexpr int TILE = 8192;               // elements in a 128x64 bf16 tile

__device__ __forceinline__ u16 f2bf(float f) {
    unsigned u = __builtin_bit_cast(unsigned, f);
    unsigned r = u + 0x7FFFu + ((u >> 16) & 1u);
    return (u16)(r >> 16);
}

// element offset within a 128x64 tile for (row, klocal), xor-swizzled 16B chunks
__device__ __forceinline__ int slot_off(int row, int kl) {
    return row * 64 + ((((kl >> 3) ^ (row & 7)) << 3) | (kl & 7));
}

// ---------------- routing ----------------
__global__ void init_kernel(int* cnt) {
    if (threadIdx.x < NEXP) cnt[threadIdx.x] = 0;
}

__global__ void hist_kernel(const int* __restrict__ groups, int* __restrict__ cnt) {
    __shared__ int lc[NEXP];
    if (threadIdx.x < NEXP) lc[threadIdx.x] = 0;
    __syncthreads();
    int i = blockIdx.x * 256 + threadIdx.x;
    atomicAdd(&lc[groups[i]], 1);
    __syncthreads();
    if (threadIdx.x < NEXP) atomicAdd(&cnt[threadIdx.x], lc[threadIdx.x]);
}

__global__ void scan_kernel(const int* cnt, int* offs, int* curs) {
    if (threadIdx.x == 0 && blockIdx.x == 0) {
        int run = 0;
        for (int e = 0; e < NEXP; ++e) {
            offs[e] = run; curs[e] = run;
            run += ((cnt[e] + 127) >> 7) << 7;   // 128-aligned segments
        }
    }
}

// rpos[i] = destination row of original row i; perm[pos] = i
__global__ void scatter_kernel(const int* __restrict__ groups, int* __restrict__ curs,
                               int* __restrict__ perm, int* __restrict__ rpos) {
    int i = blockIdx.x * 256 + threadIdx.x;
    int e = groups[i];
    int pos = atomicAdd(&curs[e], 1);
    perm[pos] = i;
    rpos[i] = pos;
}

// ---------------- fused wide prep: W1/W2 transpose | init_out | gather-x ----------------
// grid.x = 4096 (weights) + 4096 (init_out) + 2048 (gather) = 10240
__global__ __launch_bounds__(256) void prep_kernel(
        const float* __restrict__ x, const int* __restrict__ groups,
        const float* __restrict__ W1, const float* __restrict__ W2,
        const float* __restrict__ b2, float* __restrict__ out,
        const int* __restrict__ rpos,
        u16* __restrict__ xsT, u16* __restrict__ w1tT, u16* __restrict__ w2tT) {
    int bx = blockIdx.x;
    int t = threadIdx.x;
    if (bx < 4096) {
        // weight transpose+convert+tile: src [E][K][N] -> tiled [e][nt][kt][128][64]
        __shared__ float tile[64][65];
        bool isW1 = bx < 2048;
        int b = isW1 ? bx : bx - 2048;
        int e = b >> 8;
        int q = b & 255;
        int C = isW1 ? DH : DOUT;                 // N-dim
        int NTP = C >> 7;                         // n-tiles (16 / 4)
        int KTP = isW1 ? (DIN >> 6) : (DH >> 6);  // k-tiles (8 / 32)
        int rt = isW1 ? (q >> 5) : (q >> 3);      // k 64-tile idx
        int ct = isW1 ? (q & 31) : (q & 7);       // n 64-tile idx
        const float* s = (isW1 ? W1 : W2) + (size_t)e * (isW1 ? DIN * DH : DH * DOUT);
        u16* d = isW1 ? w1tT : w2tT;
        int r0 = rt * 64, c0 = ct * 64;
        for (int i = 0; i < 4; ++i) {
            int r = (t >> 4) + i * 16;
            int c = (t & 15) * 4;
            const float4 v = *(const float4*)&s[(size_t)(r0 + r) * C + c0 + c];
            tile[r][c] = v.x; tile[r][c + 1] = v.y; tile[r][c + 2] = v.z; tile[r][c + 3] = v.w;
        }
        __syncthreads();
        for (int i = 0; i < 4; ++i) {
            int c = (t >> 4) + i * 16;    // n-local
            int r = (t & 15) * 4;         // k-local, 4 consecutive
            int n = c0 + c, k = r0 + r;
            ushort4 o;
            o.x = f2bf(tile[r][c]); o.y = f2bf(tile[r + 1][c]);
            o.z = f2bf(tile[r + 2][c]); o.w = f2bf(tile[r + 3][c]);
            size_t off = ((size_t)(e * NTP + (n >> 7)) * KTP + (k >> 6)) * TILE
                         + slot_off(n & 127, k & 63);
            *(ushort4*)&d[off] = o;
        }
    } else if (bx < 8192) {
        // out[b][:] = b2[groups[b]][:]  (pass B accumulates via atomics)
        int idx = (bx - 4096) * 256 + t;
        int row = idx >> 7;
        int c = (idx & 127) * 4;
        int g = groups[row];
        *(float4*)&out[(size_t)row * DOUT + c] = *(const float4*)&b2[(size_t)g * DOUT + c];
    } else {
        // gather-x: 4 rows per block, 64 lanes per row, 8 elems/lane
        int r = t >> 6, lane = t & 63;
        int i = (bx - 8192) * 4 + r;
        int pos = rpos[i];
        int k = lane * 8;
        const float4 a = *(const float4*)&x[(size_t)i * DIN + k];
        const float4 b = *(const float4*)&x[(size_t)i * DIN + k + 4];
        ushort8 o;
        o[0] = f2bf(a.x); o[1] = f2bf(a.y); o[2] = f2bf(a.z); o[3] = f2bf(a.w);
        o[4] = f2bf(b.x); o[5] = f2bf(b.y); o[6] = f2bf(b.z); o[7] = f2bf(b.w);
        int lp = pos & 127;
        size_t off = (size_t)(pos >> 7) * 8 * TILE + (size_t)(k >> 6) * TILE
                     + slot_off(lp, k & 63);
        *(ushort8*)&xsT[off] = o;
    }
}

// ---------------- GEMM building blocks ----------------
__device__ __forceinline__ void stage_tile(const u16* Atile, const u16* Btile,
                                           u16* As, u16* Bs, int tid, int w) {
    for (int j = 0; j < 4; ++j) {
        int off = (j * 256 + w * 64) * 8;            // wave-uniform; HW adds lane*16B
        const u16* ga = Atile + (size_t)(j * 256 + tid) * 8;   // contiguous 1KB per wave
        const u16* gb = Btile + (size_t)(j * 256 + tid) * 8;
        __builtin_amdgcn_global_load_lds(GLOBAL_AS(ga), LDS_AS(As + off), 16, 0, 0);
        __builtin_amdgcn_global_load_lds(GLOBAL_AS(gb), LDS_AS(Bs + off), 16, 0, 0);
    }
}

__device__ __forceinline__ void compute_tile(const u16* As, const u16* Bs, floatx4 acc[4][4],
                                             int wm, int wn, int q, int li) {
    for (int s = 0; s < 2; ++s) {
        int c0 = s * 4 + q;
        bf16x8 af[4], bfr[4];
        for (int fm = 0; fm < 4; ++fm) {
            int m = wm * 64 + fm * 16 + li;
            af[fm] = *(const bf16x8*)&As[m * 64 + ((c0 ^ (m & 7)) << 3)];
        }
        for (int fn = 0; fn < 4; ++fn) {
            int n = wn * 64 + fn * 16 + li;
            bfr[fn] = *(const bf16x8*)&Bs[n * 64 + ((c0 ^ (n & 7)) << 3)];
        }
        for (int fm = 0; fm < 4; ++fm)
            for (int fn = 0; fn < 4; ++fn)
                acc[fm][fn] = __builtin_amdgcn_mfma_f32_16x16x32_bf16(
                    af[fm], bfr[fn], acc[fm][fn], 0, 0, 0);
    }
}

// 128x128 tile, 8 phases of BK=64, SINGLE-buffered 32KB LDS (4 blocks/CU; cross-block
// wave overlap hides the per-phase vmcnt drain — m114/m97 structure).
// Grid 1-D: e = bx&7 (XCD affinity). Pass A: 8x16x8=1024. Pass B: 8x4x4x8=1024.
template <bool RELU>
__global__ __launch_bounds__(256) void gemm_tiles(
        const u16* __restrict__ At, const u16* __restrict__ Bt,
        const float* __restrict__ bias, u16* __restrict__ hsT,
        float* __restrict__ out_f, const int* __restrict__ cnt,
        const int* __restrict__ offs, const int* __restrict__ perm) {
    int bx = blockIdx.x;
    int e = bx & 7;
    int r = bx >> 3;
    int nt, ks, mt0;
    if (RELU) { nt = r & 15; mt0 = r >> 4; ks = 0; }
    else      { nt = r & 3; r >>= 2; ks = r & 3; mt0 = r >> 2; }
    int count = cnt[e];
    int seg = offs[e];

    __shared__ u16 As[TILE];
    __shared__ u16 Bs[TILE];

    int tid = threadIdx.x;
    int l = tid & 63, w = tid >> 6;
    int wm = w & 1, wn = w >> 1;
    int q = l >> 4, li = l & 15;

    for (int mt = mt0; mt * 128 < count; mt += MTL) {
        int mtG = (seg >> 7) + mt;
        const u16* Abase;
        const u16* Bbase;
        if (RELU) {
            Abase = At + (size_t)mtG * 8 * TILE;
            Bbase = Bt + (size_t)(e * 16 + nt) * 8 * TILE;
        } else {
            Abase = At + ((size_t)mtG * 32 + ks * 8) * TILE;
            Bbase = Bt + ((size_t)(e * 4 + nt) * 32 + ks * 8) * TILE;
        }

        floatx4 acc[4][4];
        for (int a = 0; a < 4; ++a)
            for (int b = 0; b < 4; ++b) acc[a][b] = (floatx4)0.0f;

        for (int p = 0; p < 8; ++p) {
            __syncthreads();   // protect previous phase's LDS reads
            stage_tile(Abase + p * TILE, Bbase + p * TILE, As, Bs, tid, w);
            __syncthreads();   // vmcnt drain; other resident blocks compute meanwhile
            compute_tile(As, Bs, acc, wm, wn, q, li);
        }

        // epilogue: C/D layout col=lane&15, row=(lane>>4)*4+reg
        for (int fn = 0; fn < 4; ++fn) {
            int ncol = nt * 128 + wn * 64 + fn * 16 + li;
            float bv = RELU ? bias[(size_t)e * DH + ncol] : 0.0f;
            size_t tb = RELU ? ((size_t)mtG * 32 + (ncol >> 6)) * TILE : 0;
            for (int fm = 0; fm < 4; ++fm) {
                int lrow0 = wm * 64 + fm * 16 + q * 4;
                for (int rr = 0; rr < 4; ++rr) {
                    int lrow = lrow0 + rr;
                    int mrow = mt * 128 + lrow;
                    if (mrow < count) {
                        float v = acc[fm][fn][rr] + bv;
                        if (RELU) {
                            v = v > 0.0f ? v : 0.0f;
                            hsT[tb + slot_off(lrow, ncol & 63)] = f2bf(v);
                        } else {
                            int orow = perm[seg + mrow];
                            atomicAdd(&out_f[(size_t)orow * DOUT + ncol], v);
                        }
                    }
                }
            }
        }
    }
}

// ---------------- launch ----------------
extern "C" void kernel_launch(void* const* d_in, const int* in_sizes, int n_in,
                              void* d_out, int out_size, void* d_ws, size_t ws_size,
                              hipStream_t stream) {
    const float* x = (const float*)d_in[0];
    const int* groups = (const int*)d_in[1];
    const float* W1 = (const float*)d_in[2];
    const float* b1 = (const float*)d_in[3];
    const float* W2 = (const float*)d_in[4];
    const float* b2 = (const float*)d_in[5];
    float* out = (float*)d_out;

    char* ws = (char*)d_ws;
    size_t o = 0;
    auto alloc = [&](size_t bytes) {
        void* p = ws + o;
        o = (o + bytes + 255) & ~(size_t)255;
        return p;
    };
    int* cnt = (int*)alloc(NEXP * 4);
    int* offs = (int*)alloc(NEXP * 4);
    int* curs = (int*)alloc(NEXP * 4);
    int* perm = (int*)alloc((size_t)ROWCAP * 4);
    int* rpos = (int*)alloc((size_t)NB * 4);
    u16* xsT = (u16*)alloc((size_t)(ROWCAP / 128) * 8 * TILE * 2);    // ~9.4 MB
    u16* w1tT = (u16*)alloc((size_t)NEXP * DIN * DH * 2);             // 16.8 MB
    u16* w2tT = (u16*)alloc((size_t)NEXP * DH * DOUT * 2);            // 16.8 MB
    u16* hsT = (u16*)alloc((size_t)(ROWCAP / 128) * 32 * TILE * 2);   // ~37.7 MB

    init_kernel<<<1, 64, 0, stream>>>(cnt);
    hist_kernel<<<NB / 256, 256, 0, stream>>>(groups, cnt);
    scan_kernel<<<1, 64, 0, stream>>>(cnt, offs, curs);
    scatter_kernel<<<NB / 256, 256, 0, stream>>>(groups, curs, perm, rpos);
    prep_kernel<<<10240, 256, 0, stream>>>(x, groups, W1, W2, b2, out,
                                           rpos, xsT, w1tT, w2tT);
    // pass A: h = relu(x @ W1 + b1)
    gemm_tiles<true><<<NEXP * 16 * MTL, 256, 0, stream>>>(
        xsT, w1tT, b1, hsT, nullptr, cnt, offs, perm);
    // pass B: out += h @ W2 (4-way k-split, atomic)
    gemm_tiles<false><<<NEXP * 4 * 4 * MTL, 256, 0, stream>>>(
        hsT, w2tT, nullptr, nullptr, out, cnt, offs, perm);
}

// Round 6
// 300.456 us; speedup vs baseline: 1.0596x; 1.0467x over previous
//
#include <hip/hip_runtime.h>
#include <hip/hip_bf16.h>

typedef unsigned short u16;
typedef __bf16 bf16x8 __attribute__((ext_vector_type(8)));
typedef float floatx4 __attribute__((ext_vector_type(4)));
typedef unsigned short ushort8 __attribute__((ext_vector_type(8)));

#define GLOBAL_AS(p) ((const __attribute__((address_space(1))) void*)(p))
#define LDS_AS(p) ((__attribute__((address_space(3))) void*)(p))

constexpr int NB = 8192;
constexpr int DIN = 512;
constexpr int DH = 2048;
constexpr int DOUT = 512;
constexpr int NEXP = 8;
constexpr int ROWCAP = NB + NEXP * 128;  // 128-padded segments
constexpr int MTLA = 8;                  // pass A launched m-tiles/expert
constexpr int MTLB = 8;                  // pass B launched m-tiles/expert
constexpr int TILE = 8192;               // elements in a 128x64 bf16 tile

__device__ __forceinline__ u16 f2bf(float f) {
    unsigned u = __builtin_bit_cast(unsigned, f);
    unsigned r = u + 0x7FFFu + ((u >> 16) & 1u);
    return (u16)(r >> 16);
}

// element offset within a 128x64 tile for (row, klocal), xor-swizzled 16B chunks
__device__ __forceinline__ int slot_off(int row, int kl) {
    return row * 64 + ((((kl >> 3) ^ (row & 7)) << 3) | (kl & 7));
}

// ---------------- routing ----------------
__global__ void init_kernel(int* cnt) {
    if (threadIdx.x < NEXP) cnt[threadIdx.x] = 0;
}

__global__ void hist_kernel(const int* __restrict__ groups, int* __restrict__ cnt) {
    __shared__ int lc[NEXP * 16];        // 16 sub-counters per expert: low contention
    int t = threadIdx.x;
    if (t < NEXP * 16) lc[t] = 0;
    __syncthreads();
    int i = blockIdx.x * 256 + t;
    atomicAdd(&lc[groups[i] * 16 + (t & 15)], 1);
    __syncthreads();
    if (t < NEXP) {
        int s = 0;
        for (int j = 0; j < 16; ++j) s += lc[t * 16 + j];
        atomicAdd(&cnt[t], s);
    }
}

__global__ void scan_kernel(const int* cnt, int* offs, int* curs) {
    if (threadIdx.x == 0 && blockIdx.x == 0) {
        int run = 0;
        for (int e = 0; e < NEXP; ++e) {
            offs[e] = run; curs[e] = run;
            run += ((cnt[e] + 127) >> 7) << 7;   // 128-aligned segments
        }
    }
}

// rpos[i] = destination row of original row i; perm[pos] = i
__global__ void scatter_kernel(const int* __restrict__ groups, int* __restrict__ curs,
                               int* __restrict__ perm, int* __restrict__ rpos) {
    int i = blockIdx.x * 256 + threadIdx.x;
    int e = groups[i];
    int pos = atomicAdd(&curs[e], 1);
    perm[pos] = i;
    rpos[i] = pos;
}

// ---------------- fused wide prep: W1/W2 transpose+tile | gather-x ----------------
// grid.x = 4096 (weights) + 2048 (gather) = 6144
__global__ __launch_bounds__(256) void prep_kernel(
        const float* __restrict__ x, const float* __restrict__ W1,
        const float* __restrict__ W2, const int* __restrict__ rpos,
        u16* __restrict__ xsT, u16* __restrict__ w1tT, u16* __restrict__ w2tT) {
    int bx = blockIdx.x;
    int t = threadIdx.x;
    if (bx < 4096) {
        // weight transpose+convert+tile: src [E][K][N] -> tiled [e][nt][kt][128][64]
        __shared__ float tile[64][65];
        bool isW1 = bx < 2048;
        int b = isW1 ? bx : bx - 2048;
        int e = b >> 8;
        int q = b & 255;
        int C = isW1 ? DH : DOUT;                 // N-dim
        int NTP = C >> 7;                         // n-tiles (16 / 4)
        int KTP = isW1 ? (DIN >> 6) : (DH >> 6);  // k-tiles (8 / 32)
        int rt = isW1 ? (q >> 5) : (q >> 3);      // k 64-tile idx
        int ct = isW1 ? (q & 31) : (q & 7);       // n 64-tile idx
        const float* s = (isW1 ? W1 : W2) + (size_t)e * (isW1 ? DIN * DH : DH * DOUT);
        u16* d = isW1 ? w1tT : w2tT;
        int r0 = rt * 64, c0 = ct * 64;
        for (int i = 0; i < 4; ++i) {
            int r = (t >> 4) + i * 16;
            int c = (t & 15) * 4;
            const float4 v = *(const float4*)&s[(size_t)(r0 + r) * C + c0 + c];
            tile[r][c] = v.x; tile[r][c + 1] = v.y; tile[r][c + 2] = v.z; tile[r][c + 3] = v.w;
        }
        __syncthreads();
        for (int i = 0; i < 4; ++i) {
            int c = (t >> 4) + i * 16;    // n-local
            int r = (t & 15) * 4;         // k-local, 4 consecutive
            int n = c0 + c, k = r0 + r;
            ushort4 o;
            o.x = f2bf(tile[r][c]); o.y = f2bf(tile[r + 1][c]);
            o.z = f2bf(tile[r + 2][c]); o.w = f2bf(tile[r + 3][c]);
            size_t off = ((size_t)(e * NTP + (n >> 7)) * KTP + (k >> 6)) * TILE
                         + slot_off(n & 127, k & 63);
            *(ushort4*)&d[off] = o;
        }
    } else {
        // gather-x: 4 rows per block, 64 lanes per row, 8 elems/lane
        int r = t >> 6, lane = t & 63;
        int i = (bx - 4096) * 4 + r;
        int pos = rpos[i];
        int k = lane * 8;
        const float4 a = *(const float4*)&x[(size_t)i * DIN + k];
        const float4 b = *(const float4*)&x[(size_t)i * DIN + k + 4];
        ushort8 o;
        o[0] = f2bf(a.x); o[1] = f2bf(a.y); o[2] = f2bf(a.z); o[3] = f2bf(a.w);
        o[4] = f2bf(b.x); o[5] = f2bf(b.y); o[6] = f2bf(b.z); o[7] = f2bf(b.w);
        int lp = pos & 127;
        size_t off = (size_t)(pos >> 7) * 8 * TILE + (size_t)(k >> 6) * TILE
                     + slot_off(lp, k & 63);
        *(ushort8*)&xsT[off] = o;
    }
}

// ---------------- GEMM building blocks ----------------
__device__ __forceinline__ void stage_tile(const u16* Atile, const u16* Btile,
                                           u16* As, u16* Bs, int tid, int w) {
    for (int j = 0; j < 4; ++j) {
        int off = (j * 256 + w * 64) * 8;            // wave-uniform; HW adds lane*16B
        const u16* ga = Atile + (size_t)(j * 256 + tid) * 8;   // contiguous 1KB per wave
        const u16* gb = Btile + (size_t)(j * 256 + tid) * 8;
        __builtin_amdgcn_global_load_lds(GLOBAL_AS(ga), LDS_AS(As + off), 16, 0, 0);
        __builtin_amdgcn_global_load_lds(GLOBAL_AS(gb), LDS_AS(Bs + off), 16, 0, 0);
    }
}

__device__ __forceinline__ void compute_tile(const u16* As, const u16* Bs, floatx4 acc[4][4],
                                             int wm, int wn, int q, int li) {
    for (int s = 0; s < 2; ++s) {
        int c0 = s * 4 + q;
        bf16x8 af[4], bfr[4];
        for (int fm = 0; fm < 4; ++fm) {
            int m = wm * 64 + fm * 16 + li;
            af[fm] = *(const bf16x8*)&As[m * 64 + ((c0 ^ (m & 7)) << 3)];
        }
        for (int fn = 0; fn < 4; ++fn) {
            int n = wn * 64 + fn * 16 + li;
            bfr[fn] = *(const bf16x8*)&Bs[n * 64 + ((c0 ^ (n & 7)) << 3)];
        }
        for (int fm = 0; fm < 4; ++fm)
            for (int fn = 0; fn < 4; ++fn)
                acc[fm][fn] = __builtin_amdgcn_mfma_f32_16x16x32_bf16(
                    af[fm], bfr[fn], acc[fm][fn], 0, 0, 0);
    }
}

// 128x128 tile, KT phases of BK=64, single-buffered 32KB LDS, tile-contiguous operands,
// e = bx&7 XCD affinity.
// Pass A (RELU): KT=8; epilogue relu+bias -> LDS tile image -> contiguous bf16 stores.
// Pass B: KT=32, no k-split; epilogue adds b2, one fp32 store per out element (no atomics).
template <bool RELU, int KT, int NT, int MTL>
__global__ __launch_bounds__(256) void gemm_tiles(
        const u16* __restrict__ At, const u16* __restrict__ Bt,
        const float* __restrict__ bias, u16* __restrict__ hsT,
        float* __restrict__ out_f, const int* __restrict__ cnt,
        const int* __restrict__ offs, const int* __restrict__ perm) {
    int bx = blockIdx.x;
    int e = bx & 7;
    int r = bx >> 3;
    int nt = r % NT;
    int mt0 = r / NT;
    int count = cnt[e];
    int seg = offs[e];

    __shared__ u16 As[TILE];
    __shared__ u16 Bs[TILE];

    int tid = threadIdx.x;
    int l = tid & 63, w = tid >> 6;
    int wm = w & 1, wn = w >> 1;
    int q = l >> 4, li = l & 15;

    for (int mt = mt0; mt * 128 < count; mt += MTL) {
        int mtG = (seg >> 7) + mt;
        const u16* Abase = At + (size_t)mtG * KT * TILE;
        const u16* Bbase = Bt + (size_t)(e * NT + nt) * KT * TILE;

        floatx4 acc[4][4];
        for (int a = 0; a < 4; ++a)
            for (int b = 0; b < 4; ++b) acc[a][b] = (floatx4)0.0f;

        for (int p = 0; p < KT; ++p) {
            __syncthreads();   // protect previous phase's LDS reads
            stage_tile(Abase + p * TILE, Bbase + p * TILE, As, Bs, tid, w);
            __syncthreads();   // vmcnt drain; other resident blocks compute meanwhile
            compute_tile(As, Bs, acc, wm, wn, q, li);
        }

        // epilogue: C/D layout col=lane&15, row=(lane>>4)*4+reg
        if (RELU) {
            // stage 128x128 bf16 result in LDS as two 128x64 tile images, then
            // dump with full-line contiguous stores (kills 2x write amplification)
            __syncthreads();
            u16* img = wn ? Bs : As;     // wn selects k-half image; wm rows disjoint
            for (int fn = 0; fn < 4; ++fn) {
                int cl = fn * 16 + li;   // 0..63 within image
                float bv = bias[(size_t)e * DH + nt * 128 + wn * 64 + cl];
                for (int fm = 0; fm < 4; ++fm) {
                    int lrow0 = wm * 64 + fm * 16 + q * 4;
                    for (int rr = 0; rr < 4; ++rr) {
                        float v = acc[fm][fn][rr] + bv;
                        v = v > 0.0f ? v : 0.0f;
                        img[slot_off(lrow0 + rr, cl)] = f2bf(v);
                    }
                }
            }
            __syncthreads();
            int t2 = tid & 127;
            const u16* simg = (tid < 128) ? As : Bs;
            u16* dst = hsT + ((size_t)mtG * (DH / 64) + nt * 2 + (tid < 128 ? 0 : 1)) * TILE
                       + t2 * 64;
            for (int j = 0; j < 8; ++j)
                *(ushort8*)&dst[j * 8] = *(const ushort8*)&simg[t2 * 64 + j * 8];
        } else {
            for (int fn = 0; fn < 4; ++fn) {
                int ncol = nt * 128 + wn * 64 + fn * 16 + li;
                float bv = bias[(size_t)e * DOUT + ncol];
                for (int fm = 0; fm < 4; ++fm) {
                    int lrow0 = wm * 64 + fm * 16 + q * 4;
                    for (int rr = 0; rr < 4; ++rr) {
                        int mrow = mt * 128 + lrow0 + rr;
                        if (mrow < count) {
                            int orow = perm[seg + mrow];
                            out_f[(size_t)orow * DOUT + ncol] = acc[fm][fn][rr] + bv;
                        }
                    }
                }
            }
        }
    }
}

// ---------------- launch ----------------
extern "C" void kernel_launch(void* const* d_in, const int* in_sizes, int n_in,
                              void* d_out, int out_size, void* d_ws, size_t ws_size,
                              hipStream_t stream) {
    const float* x = (const float*)d_in[0];
    const int* groups = (const int*)d_in[1];
    const float* W1 = (const float*)d_in[2];
    const float* b1 = (const float*)d_in[3];
    const float* W2 = (const float*)d_in[4];
    const float* b2 = (const float*)d_in[5];
    float* out = (float*)d_out;

    char* ws = (char*)d_ws;
    size_t o = 0;
    auto alloc = [&](size_t bytes) {
        void* p = ws + o;
        o = (o + bytes + 255) & ~(size_t)255;
        return p;
    };
    int* cnt = (int*)alloc(NEXP * 4);
    int* offs = (int*)alloc(NEXP * 4);
    int* curs = (int*)alloc(NEXP * 4);
    int* perm = (int*)alloc((size_t)ROWCAP * 4);
    int* rpos = (int*)alloc((size_t)NB * 4);
    u16* xsT = (u16*)alloc((size_t)(ROWCAP / 128) * 8 * TILE * 2);    // ~9.4 MB
    u16* w1tT = (u16*)alloc((size_t)NEXP * DIN * DH * 2);             // 16.8 MB
    u16* w2tT = (u16*)alloc((size_t)NEXP * DH * DOUT * 2);            // 16.8 MB
    u16* hsT = (u16*)alloc((size_t)(ROWCAP / 128) * 32 * TILE * 2);   // ~37.7 MB

    init_kernel<<<1, 64, 0, stream>>>(cnt);
    hist_kernel<<<NB / 256, 256, 0, stream>>>(groups, cnt);
    scan_kernel<<<1, 64, 0, stream>>>(cnt, offs, curs);
    scatter_kernel<<<NB / 256, 256, 0, stream>>>(groups, curs, perm, rpos);
    prep_kernel<<<6144, 256, 0, stream>>>(x, W1, W2, rpos, xsT, w1tT, w2tT);
    // pass A: h = relu(x @ W1 + b1); 8 x 16nt x 8mt = 1024 blocks, KT=8
    gemm_tiles<true, 8, 16, MTLA><<<NEXP * 16 * MTLA, 256, 0, stream>>>(
        xsT, w1tT, b1, hsT, nullptr, cnt, offs, perm);
    // pass B: out = h @ W2 + b2; 8 x 4nt x 8mt = 256 blocks, KT=32, no atomics
    gemm_tiles<false, 32, 4, MTLB><<<NEXP * 4 * MTLB, 256, 0, stream>>>(
        hsT, w2tT, b2, nullptr, out, cnt, offs, perm);
}

// Round 7
// 266.217 us; speedup vs baseline: 1.1958x; 1.1286x over previous
//
#include <hip/hip_runtime.h>
#include <hip/hip_bf16.h>

typedef unsigned short u16;
typedef __bf16 bf16x8 __attribute__((ext_vector_type(8)));
typedef float floatx4 __attribute__((ext_vector_type(4)));
typedef unsigned short ushort8 __attribute__((ext_vector_type(8)));

#define GLOBAL_AS(p) ((const __attribute__((address_space(1))) void*)(p))
#define LDS_AS(p) ((__attribute__((address_space(3))) void*)(p))

constexpr int NB = 8192;
constexpr int DIN = 512;
constexpr int DH = 2048;
constexpr int DOUT = 512;
constexpr int NEXP = 8;
constexpr int ROWCAP = NB + NEXP * 128;  // 128-padded segments
constexpr int MTL = 9;                   // covers 9 m-tiles/expert without serial tail
constexpr int TILE = 8192;               // elements in a 128x64 bf16 tile

__device__ __forceinline__ u16 f2bf(float f) {
    unsigned u = __builtin_bit_cast(unsigned, f);
    unsigned r = u + 0x7FFFu + ((u >> 16) & 1u);
    return (u16)(r >> 16);
}

// element offset within a 128x64 tile for (row, klocal), xor-swizzled 16B chunks
__device__ __forceinline__ int slot_off(int row, int kl) {
    return row * 64 + ((((kl >> 3) ^ (row & 7)) << 3) | (kl & 7));
}

// ---------------- routing: one single-block kernel, per-wave sub-counters ----------------
__global__ void route_kernel(const int* __restrict__ groups, int* __restrict__ cnt,
                             int* __restrict__ offs, int* __restrict__ perm,
                             int* __restrict__ rpos) {
    __shared__ int wc[NEXP * 4];    // [e][wave] counts
    __shared__ int lcur[NEXP * 4];  // running positions
    int t = threadIdx.x;
    int w = t >> 6;
    if (t < NEXP * 4) wc[t] = 0;
    __syncthreads();
    for (int i = t; i < NB; i += 256) atomicAdd(&wc[groups[i] * 4 + w], 1);
    __syncthreads();
    if (t == 0) {
        int run = 0;
        for (int e = 0; e < NEXP; ++e) {
            offs[e] = run;
            int s = run;
            for (int j = 0; j < 4; ++j) { lcur[e * 4 + j] = s; s += wc[e * 4 + j]; }
            cnt[e] = s - run;
            run += (((s - run) + 127) >> 7) << 7;   // 128-aligned segments
        }
    }
    __syncthreads();
    for (int i = t; i < NB; i += 256) {
        int e = groups[i];
        int pos = atomicAdd(&lcur[e * 4 + w], 1);
        perm[pos] = i;
        rpos[i] = pos;
    }
}

// ---------------- fused wide prep: W1/W2 transpose+tile | gather-x ----------------
// grid.x = 4096 (weights) + 2048 (gather) = 6144
__global__ __launch_bounds__(256) void prep_kernel(
        const float* __restrict__ x, const float* __restrict__ W1,
        const float* __restrict__ W2, const int* __restrict__ rpos,
        u16* __restrict__ xsT, u16* __restrict__ w1tT, u16* __restrict__ w2tT) {
    int bx = blockIdx.x;
    int t = threadIdx.x;
    if (bx < 4096) {
        // weight transpose+convert+tile: src [E][K][N] -> tiled [e][nt][kt][128][64]
        __shared__ float tile[64][65];
        bool isW1 = bx < 2048;
        int b = isW1 ? bx : bx - 2048;
        int e = b >> 8;
        int q = b & 255;
        int C = isW1 ? DH : DOUT;                 // N-dim
        int NTP = C >> 7;                         // n-tiles (16 / 4)
        int KTP = isW1 ? (DIN >> 6) : (DH >> 6);  // k-tiles (8 / 32)
        int rt = isW1 ? (q >> 5) : (q >> 3);      // k 64-tile idx
        int ct = isW1 ? (q & 31) : (q & 7);       // n 64-tile idx
        const float* s = (isW1 ? W1 : W2) + (size_t)e * (isW1 ? DIN * DH : DH * DOUT);
        u16* d = isW1 ? w1tT : w2tT;
        int r0 = rt * 64, c0 = ct * 64;
        for (int i = 0; i < 4; ++i) {
            int r = (t >> 4) + i * 16;
            int c = (t & 15) * 4;
            const float4 v = *(const float4*)&s[(size_t)(r0 + r) * C + c0 + c];
            tile[r][c] = v.x; tile[r][c + 1] = v.y; tile[r][c + 2] = v.z; tile[r][c + 3] = v.w;
        }
        __syncthreads();
        for (int i = 0; i < 4; ++i) {
            int c = (t >> 4) + i * 16;    // n-local
            int r = (t & 15) * 4;         // k-local, 4 consecutive
            int n = c0 + c, k = r0 + r;
            ushort4 o;
            o.x = f2bf(tile[r][c]); o.y = f2bf(tile[r + 1][c]);
            o.z = f2bf(tile[r + 2][c]); o.w = f2bf(tile[r + 3][c]);
            size_t off = ((size_t)(e * NTP + (n >> 7)) * KTP + (k >> 6)) * TILE
                         + slot_off(n & 127, k & 63);
            *(ushort4*)&d[off] = o;
        }
    } else {
        // gather-x: 4 rows per block, 64 lanes per row, 8 elems/lane
        int r = t >> 6, lane = t & 63;
        int i = (bx - 4096) * 4 + r;
        int pos = rpos[i];
        int k = lane * 8;
        const float4 a = *(const float4*)&x[(size_t)i * DIN + k];
        const float4 b = *(const float4*)&x[(size_t)i * DIN + k + 4];
        ushort8 o;
        o[0] = f2bf(a.x); o[1] = f2bf(a.y); o[2] = f2bf(a.z); o[3] = f2bf(a.w);
        o[4] = f2bf(b.x); o[5] = f2bf(b.y); o[6] = f2bf(b.z); o[7] = f2bf(b.w);
        int lp = pos & 127;
        size_t off = (size_t)(pos >> 7) * 8 * TILE + (size_t)(k >> 6) * TILE
                     + slot_off(lp, k & 63);
        *(ushort8*)&xsT[off] = o;
    }
}

// ---------------- GEMM building blocks ----------------
__device__ __forceinline__ void stage_tile(const u16* Atile, const u16* Btile,
                                           u16* As, u16* Bs, int tid, int w) {
    for (int j = 0; j < 4; ++j) {
        int off = (j * 256 + w * 64) * 8;            // wave-uniform; HW adds lane*16B
        const u16* ga = Atile + (size_t)(j * 256 + tid) * 8;   // contiguous 1KB per wave
        const u16* gb = Btile + (size_t)(j * 256 + tid) * 8;
        __builtin_amdgcn_global_load_lds(GLOBAL_AS(ga), LDS_AS(As + off), 16, 0, 0);
        __builtin_amdgcn_global_load_lds(GLOBAL_AS(gb), LDS_AS(Bs + off), 16, 0, 0);
    }
}

__device__ __forceinline__ void compute_tile(const u16* As, const u16* Bs, floatx4 acc[4][4],
                                             int wm, int wn, int q, int li) {
    for (int s = 0; s < 2; ++s) {
        int c0 = s * 4 + q;
        bf16x8 af[4], bfr[4];
        for (int fm = 0; fm < 4; ++fm) {
            int m = wm * 64 + fm * 16 + li;
            af[fm] = *(const bf16x8*)&As[m * 64 + ((c0 ^ (m & 7)) << 3)];
        }
        for (int fn = 0; fn < 4; ++fn) {
            int n = wn * 64 + fn * 16 + li;
            bfr[fn] = *(const bf16x8*)&Bs[n * 64 + ((c0 ^ (n & 7)) << 3)];
        }
        for (int fm = 0; fm < 4; ++fm)
            for (int fn = 0; fn < 4; ++fn)
                acc[fm][fn] = __builtin_amdgcn_mfma_f32_16x16x32_bf16(
                    af[fm], bfr[fn], acc[fm][fn], 0, 0, 0);
    }
}

// ---------------- pass A: h = relu(x @ W1 + b1), bf16 tiled out ----------------
// grid = 8 experts x 16 n-tiles x 9 m-tiles = 1152, e = bx&7 (XCD affinity)
__global__ __launch_bounds__(256) void gemm_a(
        const u16* __restrict__ At, const u16* __restrict__ Bt,
        const float* __restrict__ bias, u16* __restrict__ hsT,
        const int* __restrict__ cnt, const int* __restrict__ offs) {
    int bx = blockIdx.x;
    int e = bx & 7;
    int r = bx >> 3;
    int nt = r & 15;
    int mt0 = r >> 4;
    int count = cnt[e];
    int seg = offs[e];

    __shared__ u16 As[TILE];
    __shared__ u16 Bs[TILE];

    int tid = threadIdx.x;
    int l = tid & 63, w = tid >> 6;
    int wm = w & 1, wn = w >> 1;
    int q = l >> 4, li = l & 15;

    for (int mt = mt0; mt * 128 < count; mt += MTL) {
        int mtG = (seg >> 7) + mt;
        const u16* Abase = At + (size_t)mtG * 8 * TILE;
        const u16* Bbase = Bt + (size_t)(e * 16 + nt) * 8 * TILE;

        floatx4 acc[4][4];
        for (int a = 0; a < 4; ++a)
            for (int b = 0; b < 4; ++b) acc[a][b] = (floatx4)0.0f;

        for (int p = 0; p < 8; ++p) {
            __syncthreads();
            stage_tile(Abase + p * TILE, Bbase + p * TILE, As, Bs, tid, w);
            __syncthreads();
            compute_tile(As, Bs, acc, wm, wn, q, li);
        }

        // epilogue: C/D layout col=lane&15, row=(lane>>4)*4+reg.
        // Stage 128x128 bf16 result as two 128x64 LDS tile images, then dump with
        // full-line contiguous stores.
        __syncthreads();
        u16* img = wn ? Bs : As;
        for (int fn = 0; fn < 4; ++fn) {
            int cl = fn * 16 + li;
            float bv = bias[(size_t)e * DH + nt * 128 + wn * 64 + cl];
            for (int fm = 0; fm < 4; ++fm) {
                int lrow0 = wm * 64 + fm * 16 + q * 4;
                for (int rr = 0; rr < 4; ++rr) {
                    float v = acc[fm][fn][rr] + bv;
                    v = v > 0.0f ? v : 0.0f;
                    img[slot_off(lrow0 + rr, cl)] = f2bf(v);
                }
            }
        }
        __syncthreads();
        int t2 = tid & 127;
        const u16* simg = (tid < 128) ? As : Bs;
        u16* dst = hsT + ((size_t)mtG * (DH / 64) + nt * 2 + (tid < 128 ? 0 : 1)) * TILE
                   + t2 * 64;
        for (int j = 0; j < 8; ++j)
            *(ushort8*)&dst[j * 8] = *(const ushort8*)&simg[t2 * 64 + j * 8];
    }
}

// ---------------- pass B: partial[ks] = h @ W2 over K-half, fp32 sorted layout ----------
// grid = 8 experts x 4 n-tiles x 2 k-splits x 9 m-tiles = 576
__global__ __launch_bounds__(256) void gemm_b(
        const u16* __restrict__ At, const u16* __restrict__ Bt,
        float* __restrict__ ps, const int* __restrict__ cnt,
        const int* __restrict__ offs) {
    int bx = blockIdx.x;
    int e = bx & 7;
    int r = bx >> 3;
    int nt = r & 3; r >>= 2;
    int ks = r & 1;
    int mt0 = r >> 1;
    int count = cnt[e];
    int seg = offs[e];

    __shared__ u16 As[TILE];
    __shared__ u16 Bs[TILE];

    int tid = threadIdx.x;
    int l = tid & 63, w = tid >> 6;
    int wm = w & 1, wn = w >> 1;
    int q = l >> 4, li = l & 15;

    for (int mt = mt0; mt * 128 < count; mt += MTL) {
        int mtG = (seg >> 7) + mt;
        const u16* Abase = At + ((size_t)mtG * 32 + ks * 16) * TILE;
        const u16* Bbase = Bt + (((size_t)(e * 4 + nt)) * 32 + ks * 16) * TILE;

        floatx4 acc[4][4];
        for (int a = 0; a < 4; ++a)
            for (int b = 0; b < 4; ++b) acc[a][b] = (floatx4)0.0f;

        for (int p = 0; p < 16; ++p) {
            __syncthreads();
            stage_tile(Abase + p * TILE, Bbase + p * TILE, As, Bs, tid, w);
            __syncthreads();
            compute_tile(As, Bs, acc, wm, wn, q, li);
        }

        // direct fp32 stores: each 16-lane quarter covers a 64B-aligned full sector
        float* pbase = ps + ((size_t)ks * ROWCAP + seg + mt * 128) * DOUT;
        for (int fn = 0; fn < 4; ++fn) {
            int ncol = nt * 128 + wn * 64 + fn * 16 + li;
            for (int fm = 0; fm < 4; ++fm) {
                int lrow0 = wm * 64 + fm * 16 + q * 4;
                for (int rr = 0; rr < 4; ++rr)
                    pbase[(size_t)(lrow0 + rr) * DOUT + ncol] = acc[fm][fn][rr];
            }
        }
    }
}

// ---------------- reduce: out[i] = ps[0][rpos[i]] + ps[1][rpos[i]] + b2[groups[i]] ------
__global__ __launch_bounds__(256) void reduce_b(
        const float* __restrict__ ps, const int* __restrict__ rpos,
        const int* __restrict__ groups, const float* __restrict__ b2,
        float* __restrict__ out) {
    int idx = blockIdx.x * 256 + threadIdx.x;
    int i = idx >> 7;
    int c = (idx & 127) * 4;
    int pos = rpos[i];
    int g = groups[i];
    const float4 v0 = *(const float4*)&ps[(size_t)pos * DOUT + c];
    const float4 v1 = *(const float4*)&ps[((size_t)ROWCAP + pos) * DOUT + c];
    const float4 bb = *(const float4*)&b2[(size_t)g * DOUT + c];
    float4 o;
    o.x = v0.x + v1.x + bb.x; o.y = v0.y + v1.y + bb.y;
    o.z = v0.z + v1.z + bb.z; o.w = v0.w + v1.w + bb.w;
    *(float4*)&out[(size_t)i * DOUT + c] = o;
}

// ---------------- launch ----------------
extern "C" void kernel_launch(void* const* d_in, const int* in_sizes, int n_in,
                              void* d_out, int out_size, void* d_ws, size_t ws_size,
                              hipStream_t stream) {
    const float* x = (const float*)d_in[0];
    const int* groups = (const int*)d_in[1];
    const float* W1 = (const float*)d_in[2];
    const float* b1 = (const float*)d_in[3];
    const float* W2 = (const float*)d_in[4];
    const float* b2 = (const float*)d_in[5];
    float* out = (float*)d_out;

    char* ws = (char*)d_ws;
    size_t o = 0;
    auto alloc = [&](size_t bytes) {
        void* p = ws + o;
        o = (o + bytes + 255) & ~(size_t)255;
        return p;
    };
    int* cnt = (int*)alloc(NEXP * 4);
    int* offs = (int*)alloc(NEXP * 4);
    int* perm = (int*)alloc((size_t)ROWCAP * 4);
    int* rpos = (int*)alloc((size_t)NB * 4);
    u16* xsT = (u16*)alloc((size_t)(ROWCAP / 128) * 8 * TILE * 2);    // ~9.4 MB
    u16* w1tT = (u16*)alloc((size_t)NEXP * DIN * DH * 2);             // 16.8 MB
    u16* w2tT = (u16*)alloc((size_t)NEXP * DH * DOUT * 2);            // 16.8 MB
    u16* hsT = (u16*)alloc((size_t)(ROWCAP / 128) * 32 * TILE * 2);   // ~37.7 MB
    float* ps = (float*)alloc((size_t)2 * ROWCAP * DOUT * 4);         // ~37.7 MB

    route_kernel<<<1, 256, 0, stream>>>(groups, cnt, offs, perm, rpos);
    prep_kernel<<<6144, 256, 0, stream>>>(x, W1, W2, rpos, xsT, w1tT, w2tT);
    gemm_a<<<NEXP * 16 * MTL, 256, 0, stream>>>(xsT, w1tT, b1, hsT, cnt, offs);
    gemm_b<<<NEXP * 4 * 2 * MTL, 256, 0, stream>>>(hsT, w2tT, ps, cnt, offs);
    reduce_b<<<(NB * (DOUT / 4)) / 256, 256, 0, stream>>>(ps, rpos, groups, b2, out);
}